// Round 1
// baseline (405.935 us; speedup 1.0000x reference)
//
#include <hip/hip_runtime.h>
#include <hip/hip_bf16.h>
#include <stdint.h>

#define B_   2
#define S_   2048
#define D_   1024
#define H_   16
#define DH_  64
#define HID_ 4096
#define M_   4096  // B_*S_

typedef __bf16 bf16x8 __attribute__((ext_vector_type(8)));
typedef float  f32x4  __attribute__((ext_vector_type(4)));

typedef const uint32_t __attribute__((address_space(1))) u32g;
typedef uint32_t       __attribute__((address_space(3))) u32l;

__device__ __forceinline__ uint16_t f2bf(float f) {
  uint32_t u = __builtin_bit_cast(uint32_t, f);
  u += 0x7FFFu + ((u >> 16) & 1u);   // RNE
  return (uint16_t)(u >> 16);
}

__device__ __forceinline__ void gload_lds16(const void* g, void* l) {
  __builtin_amdgcn_global_load_lds((u32g*)g, (u32l*)l, 16, 0, 0);
}

// ---------- weight convert + transpose: W (K,N) f32 -> WT (N,K) bf16 ----------
__global__ void wconv_t(const float* __restrict__ W, uint16_t* __restrict__ WT,
                        int K, int N) {
  __shared__ float tile[32][33];
  int n0 = blockIdx.x * 32, k0 = blockIdx.y * 32;
  int tx = threadIdx.x, ty = threadIdx.y;  // (32,8)
#pragma unroll
  for (int i = 0; i < 4; ++i)
    tile[ty + i * 8][tx] = W[(size_t)(k0 + ty + i * 8) * N + n0 + tx];
  __syncthreads();
#pragma unroll
  for (int i = 0; i < 4; ++i)
    WT[(size_t)(n0 + ty + i * 8) * K + k0 + tx] = f2bf(tile[tx][ty + i * 8]);
}

// ---------- layernorm: f32 row (1024) -> bf16 ----------
__global__ __launch_bounds__(256) void ln_k(const float* __restrict__ x,
                                            const float* __restrict__ sc,
                                            const float* __restrict__ sh,
                                            uint16_t* __restrict__ out) {
  int row = blockIdx.x;
  int t = threadIdx.x;
  float4 v = reinterpret_cast<const float4*>(x + (size_t)row * D_)[t];
  float s = v.x + v.y + v.z + v.w;
  float ss = v.x * v.x + v.y * v.y + v.z * v.z + v.w * v.w;
#pragma unroll
  for (int off = 32; off >= 1; off >>= 1) {
    s += __shfl_xor(s, off);
    ss += __shfl_xor(ss, off);
  }
  __shared__ float red[8];
  int wid = t >> 6, lane = t & 63;
  if (lane == 0) { red[wid] = s; red[wid + 4] = ss; }
  __syncthreads();
  s = red[0] + red[1] + red[2] + red[3];
  ss = red[4] + red[5] + red[6] + red[7];
  float mean = s * (1.0f / D_);
  float var = ss * (1.0f / D_) - mean * mean;
  float rstd = rsqrtf(var + 1e-5f);
  float4 g = reinterpret_cast<const float4*>(sc)[t];
  float4 b = reinterpret_cast<const float4*>(sh)[t];
  ushort4 o;
  o.x = f2bf(g.x * (v.x - mean) * rstd + b.x);
  o.y = f2bf(g.y * (v.y - mean) * rstd + b.y);
  o.z = f2bf(g.z * (v.z - mean) * rstd + b.z);
  o.w = f2bf(g.w * (v.w - mean) * rstd + b.w);
  reinterpret_cast<ushort4*>(out + (size_t)row * D_)[t] = o;
}

// ---------- transpose V (bh,s,dh) -> VT (bh,dh,s), bf16 ----------
__global__ void vtrans_k(const uint16_t* __restrict__ V, uint16_t* __restrict__ VT) {
  __shared__ uint16_t tile[32][33];
  int s0 = blockIdx.x * 32, d0 = blockIdx.y * 32, bh = blockIdx.z;
  int tx = threadIdx.x, ty = threadIdx.y;  // (32,8)
  const uint16_t* vb = V + (size_t)bh * S_ * DH_;
  uint16_t* vtb = VT + (size_t)bh * DH_ * S_;
#pragma unroll
  for (int i = 0; i < 4; ++i)
    tile[ty + i * 8][tx] = vb[(size_t)(s0 + ty + i * 8) * DH_ + d0 + tx];
  __syncthreads();
#pragma unroll
  for (int i = 0; i < 4; ++i)
    vtb[(size_t)(d0 + ty + i * 8) * S_ + s0 + tx] = tile[tx][ty + i * 8];
}

// ---------- GEMM: A (M,K) bf16 x BT (N,K) bf16, 128x128 tile, BK=64 ----------
// EPI 0: qkv head-split bf16 store; 1: f32 out = resid + acc + bias; 2: gelu bf16
template <int EPI>
__global__ __launch_bounds__(256) void gemm_bt(
    const uint16_t* __restrict__ A, const uint16_t* __restrict__ BT,
    void* __restrict__ Cout, const float* __restrict__ bias,
    const float* __restrict__ resid, int M, int N, int K) {
  __shared__ uint16_t Asm_[128 * 64];
  __shared__ uint16_t Bsm_[128 * 64];
  int t = threadIdx.x;
  int lane = t & 63, wid = t >> 6;
  int wr = wid >> 1, wc = wid & 1;
  int m0 = blockIdx.y * 128, n0 = blockIdx.x * 128;
  int l15 = lane & 15, lk8 = (lane >> 4) * 8;
  f32x4 acc[4][4] = {};
  for (int k0 = 0; k0 < K; k0 += 64) {
    __syncthreads();
#pragma unroll
    for (int it = 0; it < 4; ++it) {
      int idx = it * 256 + t;
      int r = idx >> 3, c = (idx & 7) * 8;
      gload_lds16(A + (size_t)(m0 + r) * K + k0 + c, &Asm_[idx * 8]);
      gload_lds16(BT + (size_t)(n0 + r) * K + k0 + c, &Bsm_[idx * 8]);
    }
    __syncthreads();
#pragma unroll
    for (int kk = 0; kk < 2; ++kk) {
      bf16x8 a[4], b[4];
#pragma unroll
      for (int mi = 0; mi < 4; ++mi)
        a[mi] = *reinterpret_cast<const bf16x8*>(
            &Asm_[(wr * 64 + mi * 16 + l15) * 64 + kk * 32 + lk8]);
#pragma unroll
      for (int ni = 0; ni < 4; ++ni)
        b[ni] = *reinterpret_cast<const bf16x8*>(
            &Bsm_[(wc * 64 + ni * 16 + l15) * 64 + kk * 32 + lk8]);
#pragma unroll
      for (int mi = 0; mi < 4; ++mi)
#pragma unroll
        for (int ni = 0; ni < 4; ++ni)
          acc[mi][ni] = __builtin_amdgcn_mfma_f32_16x16x32_bf16(
              a[mi], b[ni], acc[mi][ni], 0, 0, 0);
    }
  }
  int lr4 = (lane >> 4) * 4;
#pragma unroll
  for (int mi = 0; mi < 4; ++mi) {
#pragma unroll
    for (int ni = 0; ni < 4; ++ni) {
#pragma unroll
      for (int r = 0; r < 4; ++r) {
        int gm = m0 + wr * 64 + mi * 16 + lr4 + r;
        int gn = n0 + wc * 64 + ni * 16 + l15;
        float v = acc[mi][ni][r];
        if constexpr (EPI == 0) {
          int which = gn >> 10, nc = gn & 1023;
          int h = nc >> 6, dh = nc & 63;
          int b = gm >> 11, s = gm & 2047;
          ((uint16_t*)Cout)[((size_t)which * 32 + b * 16 + h) * (S_ * 64) +
                            (size_t)s * 64 + dh] = f2bf(v);
        } else if constexpr (EPI == 1) {
          ((float*)Cout)[(size_t)gm * N + gn] =
              resid[(size_t)gm * N + gn] + v + bias[gn];
        } else {
          float u = v + bias[gn];
          float y = 0.7978845608028654f * (u + 0.044715f * u * u * u);
          float e = __expf(2.0f * y);
          float th = 1.0f - 2.0f / (e + 1.0f);  // tanh(y), inf-safe
          ((uint16_t*)Cout)[(size_t)gm * N + gn] = f2bf(0.5f * u * (1.0f + th));
        }
      }
    }
  }
}

// ---------- flash causal attention, QBLK=64 (4 waves x 16 rows), KVBLK=64 ----------
__global__ __launch_bounds__(256) void attn_k(const uint16_t* __restrict__ Q,
                                              const uint16_t* __restrict__ Kv,
                                              const uint16_t* __restrict__ VT,
                                              uint16_t* __restrict__ ctx) {
  __shared__ uint16_t Ksm[64 * 64];
  __shared__ uint16_t Vsm[64 * 64];  // holds Vt tile: [dh][key]
  __shared__ uint16_t Psm[4][16 * 64];
  int qt = blockIdx.x, bh = blockIdx.y;
  int q0 = qt * 64;
  int t = threadIdx.x, lane = t & 63, wid = t >> 6;
  int l15 = lane & 15, lk8 = (lane >> 4) * 8, lr4 = (lane >> 4) * 4;
  bf16x8 qf[2];
#pragma unroll
  for (int kk = 0; kk < 2; ++kk)
    qf[kk] = *reinterpret_cast<const bf16x8*>(
        &Q[((size_t)bh * S_ + q0 + wid * 16 + l15) * 64 + kk * 32 + lk8]);
  f32x4 o[4] = {};
  float mrow[4], lsum[4];
#pragma unroll
  for (int r = 0; r < 4; ++r) { mrow[r] = -3.0e38f; lsum[r] = 0.0f; }
  int nkt = qt + 1;
  for (int kt = 0; kt < nkt; ++kt) {
    int k0 = kt * 64;
    __syncthreads();
#pragma unroll
    for (int it = 0; it < 2; ++it) {
      int idx = it * 256 + t;
      int r = idx >> 3, c = (idx & 7) * 8;
      gload_lds16(Kv + ((size_t)bh * S_ + k0 + r) * 64 + c, &Ksm[idx * 8]);
      gload_lds16(VT + ((size_t)bh * 64 + r) * S_ + k0 + c, &Vsm[idx * 8]);
    }
    __syncthreads();
    f32x4 sf[4] = {};
#pragma unroll
    for (int kk = 0; kk < 2; ++kk)
#pragma unroll
      for (int nt = 0; nt < 4; ++nt) {
        bf16x8 kb = *reinterpret_cast<const bf16x8*>(
            &Ksm[(nt * 16 + l15) * 64 + kk * 32 + lk8]);
        sf[nt] = __builtin_amdgcn_mfma_f32_16x16x32_bf16(qf[kk], kb, sf[nt], 0, 0, 0);
      }
    float sv[4][4];
#pragma unroll
    for (int nt = 0; nt < 4; ++nt)
#pragma unroll
      for (int r = 0; r < 4; ++r) {
        float s = sf[nt][r] * 0.125f;
        int key = k0 + nt * 16 + l15;
        int qr = q0 + wid * 16 + lr4 + r;
        sv[nt][r] = (key <= qr) ? s : -3.0e38f;
      }
    float pmax[4];
#pragma unroll
    for (int r = 0; r < 4; ++r)
      pmax[r] = fmaxf(fmaxf(sv[0][r], sv[1][r]), fmaxf(sv[2][r], sv[3][r]));
#pragma unroll
    for (int off = 8; off >= 1; off >>= 1)
#pragma unroll
      for (int r = 0; r < 4; ++r)
        pmax[r] = fmaxf(pmax[r], __shfl_xor(pmax[r], off));
    float fac[4];
#pragma unroll
    for (int r = 0; r < 4; ++r) {
      float mn = fmaxf(mrow[r], pmax[r]);
      fac[r] = __expf(mrow[r] - mn);
      mrow[r] = mn;
      lsum[r] *= fac[r];
    }
#pragma unroll
    for (int dt = 0; dt < 4; ++dt)
#pragma unroll
      for (int r = 0; r < 4; ++r) o[dt][r] *= fac[r];
    float psum[4] = {0.0f, 0.0f, 0.0f, 0.0f};
#pragma unroll
    for (int nt = 0; nt < 4; ++nt)
#pragma unroll
      for (int r = 0; r < 4; ++r) {
        float p = __expf(sv[nt][r] - mrow[r]);
        psum[r] += p;
        Psm[wid][(lr4 + r) * 64 + nt * 16 + l15] = f2bf(p);
      }
#pragma unroll
    for (int off = 8; off >= 1; off >>= 1)
#pragma unroll
      for (int r = 0; r < 4; ++r) psum[r] += __shfl_xor(psum[r], off);
#pragma unroll
    for (int r = 0; r < 4; ++r) lsum[r] += psum[r];
    // PV: ctx += P (16q x 64k) @ Vt^T (64k x 64dh)
#pragma unroll
    for (int kk = 0; kk < 2; ++kk) {
      bf16x8 pa = *reinterpret_cast<const bf16x8*>(
          &Psm[wid][l15 * 64 + kk * 32 + lk8]);
#pragma unroll
      for (int dt = 0; dt < 4; ++dt) {
        bf16x8 vb = *reinterpret_cast<const bf16x8*>(
            &Vsm[(dt * 16 + l15) * 64 + kk * 32 + lk8]);
        o[dt] = __builtin_amdgcn_mfma_f32_16x16x32_bf16(pa, vb, o[dt], 0, 0, 0);
      }
    }
  }
  int b = bh >> 4, h = bh & 15;
#pragma unroll
  for (int dt = 0; dt < 4; ++dt)
#pragma unroll
    for (int r = 0; r < 4; ++r) {
      int s = q0 + wid * 16 + lr4 + r;
      int dh = dt * 16 + l15;
      ctx[((size_t)(b * S_ + s)) * D_ + h * 64 + dh] = f2bf(o[dt][r] / lsum[r]);
    }
}

extern "C" void kernel_launch(void* const* d_in, const int* in_sizes, int n_in,
                              void* d_out, int out_size, void* d_ws, size_t ws_size,
                              hipStream_t stream) {
  const float* x    = (const float*)d_in[0];
  const float* Wq   = (const float*)d_in[1];
  const float* Wk   = (const float*)d_in[2];
  const float* Wv   = (const float*)d_in[3];
  const float* Wo   = (const float*)d_in[4];
  const float* bo   = (const float*)d_in[5];
  const float* W1   = (const float*)d_in[6];
  const float* b1   = (const float*)d_in[7];
  const float* W2   = (const float*)d_in[8];
  const float* b2   = (const float*)d_in[9];
  const float* ln1s = (const float*)d_in[10];
  const float* ln1b = (const float*)d_in[11];
  const float* ln2s = (const float*)d_in[12];
  const float* ln2b = (const float*)d_in[13];
  float* out = (float*)d_out;
  char* ws = (char*)d_ws;

  const size_t MB = 1024 * 1024;
  uint16_t* WQKVT = (uint16_t*)(ws + 0);        // 6 MB  (3072 x 1024)
  uint16_t* WOT   = (uint16_t*)(ws + 6 * MB);   // 2 MB  (1024 x 1024)
  uint16_t* W1T   = (uint16_t*)(ws + 8 * MB);   // 8 MB  (4096 x 1024)
  uint16_t* W2T   = (uint16_t*)(ws + 16 * MB);  // 8 MB  (1024 x 4096)
  uint16_t* H1    = (uint16_t*)(ws + 24 * MB);  // 8 MB  (LN1 out; reused for LN2 out)
  float*    X1    = (float*)(ws + 32 * MB);     // 16 MB (attn residual, f32)
  uint16_t* QKV   = (uint16_t*)(ws + 48 * MB);  // 24 MB (q,k,v in (bh,s,dh))
  uint16_t* VTb   = (uint16_t*)(ws + 72 * MB);  // 8 MB  (v transposed (bh,dh,s))
  uint16_t* CTX   = (uint16_t*)(ws + 80 * MB);  // 8 MB
  uint16_t* FFH   = (uint16_t*)(ws + 48 * MB);  // 32 MB (reuses dead QKV/VT)

  dim3 b32x8(32, 8);
  // weight convert+transpose (bf16)
  wconv_t<<<dim3(32, 32), b32x8, 0, stream>>>(Wq, WQKVT, 1024, 1024);
  wconv_t<<<dim3(32, 32), b32x8, 0, stream>>>(Wk, WQKVT + 1024 * 1024, 1024, 1024);
  wconv_t<<<dim3(32, 32), b32x8, 0, stream>>>(Wv, WQKVT + 2 * 1024 * 1024, 1024, 1024);
  wconv_t<<<dim3(32, 32), b32x8, 0, stream>>>(Wo, WOT, 1024, 1024);
  wconv_t<<<dim3(128, 32), b32x8, 0, stream>>>(W1, W1T, 1024, 4096);
  wconv_t<<<dim3(32, 128), b32x8, 0, stream>>>(W2, W2T, 4096, 1024);

  // LN1 -> h (bf16)
  ln_k<<<M_, 256, 0, stream>>>(x, ln1s, ln1b, H1);
  // QKV projections (fused N=3072), head-split epilogue
  gemm_bt<0><<<dim3(24, 32), 256, 0, stream>>>(H1, WQKVT, QKV, nullptr, nullptr,
                                               M_, 3072, 1024);
  const uint16_t* Qp = QKV;
  const uint16_t* Kp = QKV + (size_t)32 * S_ * 64;
  const uint16_t* Vp = QKV + (size_t)64 * S_ * 64;
  vtrans_k<<<dim3(64, 2, 32), b32x8, 0, stream>>>(Vp, VTb);
  // flash causal attention
  attn_k<<<dim3(32, 32), 256, 0, stream>>>(Qp, Kp, VTb, CTX);
  // Wo projection + bias + residual -> X1 (f32)
  gemm_bt<1><<<dim3(8, 32), 256, 0, stream>>>(CTX, WOT, X1, bo, x, M_, 1024, 1024);
  // LN2 -> h2 (bf16, reuse H1)
  ln_k<<<M_, 256, 0, stream>>>(X1, ln2s, ln2b, H1);
  // FFN1 + GELU -> FFH (bf16)
  gemm_bt<2><<<dim3(32, 32), 256, 0, stream>>>(H1, W1T, FFH, b1, nullptr,
                                               M_, 4096, 1024);
  // FFN2 + bias + residual -> out (f32)
  gemm_bt<1><<<dim3(8, 32), 256, 0, stream>>>(FFH, W2T, out, b2, X1, M_, 1024, 4096);
}

// Round 2
// 379.218 us; speedup vs baseline: 1.0705x; 1.0705x over previous
//
#include <hip/hip_runtime.h>
#include <hip/hip_bf16.h>
#include <stdint.h>

#define B_   2
#define S_   2048
#define D_   1024
#define H_   16
#define DH_  64
#define HID_ 4096
#define M_   4096  // B_*S_

typedef __bf16 bf16x8 __attribute__((ext_vector_type(8)));
typedef float  f32x4  __attribute__((ext_vector_type(4)));

typedef const uint32_t __attribute__((address_space(1))) u32g;
typedef uint32_t       __attribute__((address_space(3))) u32l;

__device__ __forceinline__ uint16_t f2bf(float f) {
  uint32_t u = __builtin_bit_cast(uint32_t, f);
  u += 0x7FFFu + ((u >> 16) & 1u);   // RNE
  return (uint16_t)(u >> 16);
}

__device__ __forceinline__ void gload_lds16(const void* g, void* l) {
  __builtin_amdgcn_global_load_lds((u32g*)g, (u32l*)l, 16, 0, 0);
}

// swizzled LDS 16B read: row-major [*][64] bf16 tile, byte ^= (row&7)<<4
__device__ __forceinline__ const bf16x8* lds8p(const uint16_t* base, int row,
                                               int cole) {
  int byt = (cole * 2) ^ ((row & 7) << 4);
  return reinterpret_cast<const bf16x8*>(base + row * 64 + (byt >> 1));
}

// ---------- weight convert + transpose: W (K,N) f32 -> WT (N,K) bf16 ----------
__global__ void wconv_t(const float* __restrict__ W, uint16_t* __restrict__ WT,
                        int K, int N) {
  __shared__ float tile[32][33];
  int n0 = blockIdx.x * 32, k0 = blockIdx.y * 32;
  int tx = threadIdx.x, ty = threadIdx.y;  // (32,8)
#pragma unroll
  for (int i = 0; i < 4; ++i)
    tile[ty + i * 8][tx] = W[(size_t)(k0 + ty + i * 8) * N + n0 + tx];
  __syncthreads();
#pragma unroll
  for (int i = 0; i < 4; ++i)
    WT[(size_t)(n0 + ty + i * 8) * K + k0 + tx] = f2bf(tile[tx][ty + i * 8]);
}

// ---------- layernorm: f32 row (1024) -> bf16 ----------
__global__ __launch_bounds__(256) void ln_k(const float* __restrict__ x,
                                            const float* __restrict__ sc,
                                            const float* __restrict__ sh,
                                            uint16_t* __restrict__ out) {
  int row = blockIdx.x;
  int t = threadIdx.x;
  float4 v = reinterpret_cast<const float4*>(x + (size_t)row * D_)[t];
  float s = v.x + v.y + v.z + v.w;
  float ss = v.x * v.x + v.y * v.y + v.z * v.z + v.w * v.w;
#pragma unroll
  for (int off = 32; off >= 1; off >>= 1) {
    s += __shfl_xor(s, off);
    ss += __shfl_xor(ss, off);
  }
  __shared__ float red[8];
  int wid = t >> 6, lane = t & 63;
  if (lane == 0) { red[wid] = s; red[wid + 4] = ss; }
  __syncthreads();
  s = red[0] + red[1] + red[2] + red[3];
  ss = red[4] + red[5] + red[6] + red[7];
  float mean = s * (1.0f / D_);
  float var = ss * (1.0f / D_) - mean * mean;
  float rstd = rsqrtf(var + 1e-5f);
  float4 g = reinterpret_cast<const float4*>(sc)[t];
  float4 b = reinterpret_cast<const float4*>(sh)[t];
  ushort4 o;
  o.x = f2bf(g.x * (v.x - mean) * rstd + b.x);
  o.y = f2bf(g.y * (v.y - mean) * rstd + b.y);
  o.z = f2bf(g.z * (v.z - mean) * rstd + b.z);
  o.w = f2bf(g.w * (v.w - mean) * rstd + b.w);
  reinterpret_cast<ushort4*>(out + (size_t)row * D_)[t] = o;
}

// ---------- transpose V (bh,s,dh) -> VT (bh,dh,s), bf16 ----------
__global__ void vtrans_k(const uint16_t* __restrict__ V, uint16_t* __restrict__ VT) {
  __shared__ uint16_t tile[32][33];
  int s0 = blockIdx.x * 32, d0 = blockIdx.y * 32, bh = blockIdx.z;
  int tx = threadIdx.x, ty = threadIdx.y;  // (32,8)
  const uint16_t* vb = V + (size_t)bh * S_ * DH_;
  uint16_t* vtb = VT + (size_t)bh * DH_ * S_;
#pragma unroll
  for (int i = 0; i < 4; ++i)
    tile[ty + i * 8][tx] = vb[(size_t)(s0 + ty + i * 8) * DH_ + d0 + tx];
  __syncthreads();
#pragma unroll
  for (int i = 0; i < 4; ++i)
    vtb[(size_t)(d0 + ty + i * 8) * S_ + s0 + tx] = tile[tx][ty + i * 8];
}

// ---------- GEMM: A (M,K) bf16 x BT (N,K) bf16, 128x128 tile, BK=64 ----------
// EPI 0: qkv head-split bf16 store; 1: f32 out = resid + acc + bias; 2: gelu bf16
template <int EPI>
__global__ __launch_bounds__(256) void gemm_bt(
    const uint16_t* __restrict__ A, const uint16_t* __restrict__ BT,
    void* __restrict__ Cout, const float* __restrict__ bias,
    const float* __restrict__ resid, int M, int N, int K) {
  __shared__ uint16_t Asm_[128 * 64];
  __shared__ uint16_t Bsm_[128 * 64];
  int t = threadIdx.x;
  int lane = t & 63, wid = t >> 6;
  int wr = wid >> 1, wc = wid & 1;
  int m0 = blockIdx.y * 128, n0 = blockIdx.x * 128;
  int l15 = lane & 15, lk8 = (lane >> 4) * 8;
  f32x4 acc[4][4] = {};
  for (int k0 = 0; k0 < K; k0 += 64) {
    __syncthreads();
#pragma unroll
    for (int it = 0; it < 4; ++it) {
      int idx = it * 256 + t;
      int r = idx >> 3, c = (idx & 7) * 8;
      gload_lds16(A + (size_t)(m0 + r) * K + k0 + c, &Asm_[idx * 8]);
      gload_lds16(BT + (size_t)(n0 + r) * K + k0 + c, &Bsm_[idx * 8]);
    }
    __syncthreads();
#pragma unroll
    for (int kk = 0; kk < 2; ++kk) {
      bf16x8 a[4], b[4];
#pragma unroll
      for (int mi = 0; mi < 4; ++mi)
        a[mi] = *reinterpret_cast<const bf16x8*>(
            &Asm_[(wr * 64 + mi * 16 + l15) * 64 + kk * 32 + lk8]);
#pragma unroll
      for (int ni = 0; ni < 4; ++ni)
        b[ni] = *reinterpret_cast<const bf16x8*>(
            &Bsm_[(wc * 64 + ni * 16 + l15) * 64 + kk * 32 + lk8]);
#pragma unroll
      for (int mi = 0; mi < 4; ++mi)
#pragma unroll
        for (int ni = 0; ni < 4; ++ni)
          acc[mi][ni] = __builtin_amdgcn_mfma_f32_16x16x32_bf16(
              a[mi], b[ni], acc[mi][ni], 0, 0, 0);
    }
  }
  int lr4 = (lane >> 4) * 4;
#pragma unroll
  for (int mi = 0; mi < 4; ++mi) {
#pragma unroll
    for (int ni = 0; ni < 4; ++ni) {
#pragma unroll
      for (int r = 0; r < 4; ++r) {
        int gm = m0 + wr * 64 + mi * 16 + lr4 + r;
        int gn = n0 + wc * 64 + ni * 16 + l15;
        float v = acc[mi][ni][r];
        if constexpr (EPI == 0) {
          int which = gn >> 10, nc = gn & 1023;
          int h = nc >> 6, dh = nc & 63;
          int b = gm >> 11, s = gm & 2047;
          ((uint16_t*)Cout)[((size_t)which * 32 + b * 16 + h) * (S_ * 64) +
                            (size_t)s * 64 + dh] = f2bf(v);
        } else if constexpr (EPI == 1) {
          ((float*)Cout)[(size_t)gm * N + gn] =
              resid[(size_t)gm * N + gn] + v + bias[gn];
        } else {
          float u = v + bias[gn];
          float y = 0.7978845608028654f * (u + 0.044715f * u * u * u);
          float e = __expf(2.0f * y);
          float th = 1.0f - 2.0f / (e + 1.0f);  // tanh(y), inf-safe
          ((uint16_t*)Cout)[(size_t)gm * N + gn] = f2bf(0.5f * u * (1.0f + th));
        }
      }
    }
  }
}

// ---------- flash causal attention, QBLK=64 (4 waves x 16 rows), KVBLK=64 ----------
// K/V double-buffered + counted-vmcnt prefetch; all LDS tiles XOR-swizzled
// (byte ^= (row&7)<<4) to kill the 16-way row-stride-128B bank conflicts.
__global__ __launch_bounds__(256) void attn_k(const uint16_t* __restrict__ Q,
                                              const uint16_t* __restrict__ Kv,
                                              const uint16_t* __restrict__ VT,
                                              uint16_t* __restrict__ ctx) {
  __shared__ uint16_t Ksm[2][64 * 64];
  __shared__ uint16_t Vsm[2][64 * 64];  // Vt tile: [dh][key]
  __shared__ uint16_t Psm[4][16 * 64];
  int qt = blockIdx.x, bh = blockIdx.y;
  int q0 = qt * 64;
  int t = threadIdx.x, lane = t & 63, wid = t >> 6;
  int l15 = lane & 15, lk8 = (lane >> 4) * 8, lr4 = (lane >> 4) * 4;
  bf16x8 qf[2];
#pragma unroll
  for (int kk = 0; kk < 2; ++kk)
    qf[kk] = *reinterpret_cast<const bf16x8*>(
        &Q[((size_t)bh * S_ + q0 + wid * 16 + l15) * 64 + kk * 32 + lk8]);
  f32x4 o[4] = {};
  float mrow[4], lsum[4];
#pragma unroll
  for (int r = 0; r < 4; ++r) { mrow[r] = -3.0e38f; lsum[r] = 0.0f; }

  // stage K and Vt tiles (64x64 bf16 each) with pre-swizzled global source:
  // LDS dest stays linear (gload_lds requirement); content lands swizzled.
  auto STAGE = [&](int kt, int bufi) {
    int k0 = kt * 64;
#pragma unroll
    for (int it = 0; it < 2; ++it) {
      int idx = it * 256 + t;
      int r = idx >> 3, slot = idx & 7;
      int c = (slot ^ (r & 7)) * 8;
      gload_lds16(Kv + ((size_t)bh * S_ + k0 + r) * 64 + c, &Ksm[bufi][idx * 8]);
      gload_lds16(VT + ((size_t)bh * 64 + r) * S_ + k0 + c, &Vsm[bufi][idx * 8]);
    }
  };

  int nkt = qt + 1;
  STAGE(0, 0);
  for (int kt = 0; kt < nkt; ++kt) {
    int cur = kt & 1;
    if (kt + 1 < nkt) {
      STAGE(kt + 1, cur ^ 1);
      asm volatile("s_waitcnt vmcnt(4)" ::: "memory");  // cur tile done, next in flight
    } else {
      asm volatile("s_waitcnt vmcnt(0)" ::: "memory");
    }
    __builtin_amdgcn_s_barrier();
    asm volatile("" ::: "memory");
    __builtin_amdgcn_sched_barrier(0);
    const uint16_t* Kb = Ksm[cur];
    const uint16_t* Vb = Vsm[cur];

    f32x4 sf[4] = {};
#pragma unroll
    for (int kk = 0; kk < 2; ++kk)
#pragma unroll
      for (int nt = 0; nt < 4; ++nt) {
        bf16x8 kb = *lds8p(Kb, nt * 16 + l15, kk * 32 + lk8);
        sf[nt] = __builtin_amdgcn_mfma_f32_16x16x32_bf16(qf[kk], kb, sf[nt], 0, 0, 0);
      }
    float sv[4][4];
    if (kt == qt) {  // only the diagonal tile needs masking (wave-uniform)
#pragma unroll
      for (int nt = 0; nt < 4; ++nt)
#pragma unroll
        for (int r = 0; r < 4; ++r) {
          float s = sf[nt][r] * 0.125f;
          int key = nt * 16 + l15;
          int qr = wid * 16 + lr4 + r;
          sv[nt][r] = (key <= qr) ? s : -3.0e38f;
        }
    } else {
#pragma unroll
      for (int nt = 0; nt < 4; ++nt)
#pragma unroll
        for (int r = 0; r < 4; ++r) sv[nt][r] = sf[nt][r] * 0.125f;
    }
    float pmax[4];
#pragma unroll
    for (int r = 0; r < 4; ++r)
      pmax[r] = fmaxf(fmaxf(sv[0][r], sv[1][r]), fmaxf(sv[2][r], sv[3][r]));
#pragma unroll
    for (int off = 8; off >= 1; off >>= 1)
#pragma unroll
      for (int r = 0; r < 4; ++r)
        pmax[r] = fmaxf(pmax[r], __shfl_xor(pmax[r], off));
    float fac[4];
#pragma unroll
    for (int r = 0; r < 4; ++r) {
      float mn = fmaxf(mrow[r], pmax[r]);
      fac[r] = __expf(mrow[r] - mn);
      mrow[r] = mn;
      lsum[r] *= fac[r];
    }
#pragma unroll
    for (int dt = 0; dt < 4; ++dt)
#pragma unroll
      for (int r = 0; r < 4; ++r) o[dt][r] *= fac[r];
    float psum[4] = {0.0f, 0.0f, 0.0f, 0.0f};
#pragma unroll
    for (int nt = 0; nt < 4; ++nt)
#pragma unroll
      for (int r = 0; r < 4; ++r) {
        float p = __expf(sv[nt][r] - mrow[r]);
        psum[r] += p;
        int prow = lr4 + r, pcol = nt * 16 + l15;
        Psm[wid][prow * 64 + ((((pcol * 2) ^ ((prow & 7) << 4))) >> 1)] = f2bf(p);
      }
#pragma unroll
    for (int off = 8; off >= 1; off >>= 1)
#pragma unroll
      for (int r = 0; r < 4; ++r) psum[r] += __shfl_xor(psum[r], off);
#pragma unroll
    for (int r = 0; r < 4; ++r) lsum[r] += psum[r];
    // PV: ctx += P (16q x 64k) @ Vt^T (64k x 64dh)
#pragma unroll
    for (int kk = 0; kk < 2; ++kk) {
      bf16x8 pa = *lds8p(Psm[wid], l15, kk * 32 + lk8);
#pragma unroll
      for (int dt = 0; dt < 4; ++dt) {
        bf16x8 vb = *lds8p(Vb, dt * 16 + l15, kk * 32 + lk8);
        o[dt] = __builtin_amdgcn_mfma_f32_16x16x32_bf16(pa, vb, o[dt], 0, 0, 0);
      }
    }
    asm volatile("s_waitcnt lgkmcnt(0)" ::: "memory");  // reads of cur done
    __builtin_amdgcn_sched_barrier(0);
    __builtin_amdgcn_s_barrier();  // before next iter overwrites buffers
    asm volatile("" ::: "memory");
  }
  int b = bh >> 4, h = bh & 15;
#pragma unroll
  for (int dt = 0; dt < 4; ++dt)
#pragma unroll
    for (int r = 0; r < 4; ++r) {
      int s = q0 + wid * 16 + lr4 + r;
      int dh = dt * 16 + l15;
      ctx[((size_t)(b * S_ + s)) * D_ + h * 64 + dh] = f2bf(o[dt][r] / lsum[r]);
    }
}

extern "C" void kernel_launch(void* const* d_in, const int* in_sizes, int n_in,
                              void* d_out, int out_size, void* d_ws, size_t ws_size,
                              hipStream_t stream) {
  const float* x    = (const float*)d_in[0];
  const float* Wq   = (const float*)d_in[1];
  const float* Wk   = (const float*)d_in[2];
  const float* Wv   = (const float*)d_in[3];
  const float* Wo   = (const float*)d_in[4];
  const float* bo   = (const float*)d_in[5];
  const float* W1   = (const float*)d_in[6];
  const float* b1   = (const float*)d_in[7];
  const float* W2   = (const float*)d_in[8];
  const float* b2   = (const float*)d_in[9];
  const float* ln1s = (const float*)d_in[10];
  const float* ln1b = (const float*)d_in[11];
  const float* ln2s = (const float*)d_in[12];
  const float* ln2b = (const float*)d_in[13];
  float* out = (float*)d_out;
  char* ws = (char*)d_ws;

  const size_t MB = 1024 * 1024;
  uint16_t* WQKVT = (uint16_t*)(ws + 0);        // 6 MB  (3072 x 1024)
  uint16_t* WOT   = (uint16_t*)(ws + 6 * MB);   // 2 MB  (1024 x 1024)
  uint16_t* W1T   = (uint16_t*)(ws + 8 * MB);   // 8 MB  (4096 x 1024)
  uint16_t* W2T   = (uint16_t*)(ws + 16 * MB);  // 8 MB  (1024 x 4096)
  uint16_t* H1    = (uint16_t*)(ws + 24 * MB);  // 8 MB  (LN1 out; reused for LN2 out)
  float*    X1    = (float*)(ws + 32 * MB);     // 16 MB (attn residual, f32)
  uint16_t* QKV   = (uint16_t*)(ws + 48 * MB);  // 24 MB (q,k,v in (bh,s,dh))
  uint16_t* VTb   = (uint16_t*)(ws + 72 * MB);  // 8 MB  (v transposed (bh,dh,s))
  uint16_t* CTX   = (uint16_t*)(ws + 80 * MB);  // 8 MB
  uint16_t* FFH   = (uint16_t*)(ws + 48 * MB);  // 32 MB (reuses dead QKV/VT)

  dim3 b32x8(32, 8);
  // weight convert+transpose (bf16)
  wconv_t<<<dim3(32, 32), b32x8, 0, stream>>>(Wq, WQKVT, 1024, 1024);
  wconv_t<<<dim3(32, 32), b32x8, 0, stream>>>(Wk, WQKVT + 1024 * 1024, 1024, 1024);
  wconv_t<<<dim3(32, 32), b32x8, 0, stream>>>(Wv, WQKVT + 2 * 1024 * 1024, 1024, 1024);
  wconv_t<<<dim3(32, 32), b32x8, 0, stream>>>(Wo, WOT, 1024, 1024);
  wconv_t<<<dim3(128, 32), b32x8, 0, stream>>>(W1, W1T, 1024, 4096);
  wconv_t<<<dim3(32, 128), b32x8, 0, stream>>>(W2, W2T, 4096, 1024);

  // LN1 -> h (bf16)
  ln_k<<<M_, 256, 0, stream>>>(x, ln1s, ln1b, H1);
  // QKV projections (fused N=3072), head-split epilogue
  gemm_bt<0><<<dim3(24, 32), 256, 0, stream>>>(H1, WQKVT, QKV, nullptr, nullptr,
                                               M_, 3072, 1024);
  const uint16_t* Qp = QKV;
  const uint16_t* Kp = QKV + (size_t)32 * S_ * 64;
  const uint16_t* Vp = QKV + (size_t)64 * S_ * 64;
  vtrans_k<<<dim3(64, 2, 32), b32x8, 0, stream>>>(Vp, VTb);
  // flash causal attention
  attn_k<<<dim3(32, 32), 256, 0, stream>>>(Qp, Kp, VTb, CTX);
  // Wo projection + bias + residual -> X1 (f32)
  gemm_bt<1><<<dim3(8, 32), 256, 0, stream>>>(CTX, WOT, X1, bo, x, M_, 1024, 1024);
  // LN2 -> h2 (bf16, reuse H1)
  ln_k<<<M_, 256, 0, stream>>>(X1, ln2s, ln2b, H1);
  // FFN1 + GELU -> FFH (bf16)
  gemm_bt<2><<<dim3(32, 32), 256, 0, stream>>>(H1, W1T, FFH, b1, nullptr,
                                               M_, 4096, 1024);
  // FFN2 + bias + residual -> out (f32)
  gemm_bt<1><<<dim3(8, 32), 256, 0, stream>>>(FFH, W2T, out, b2, X1, M_, 1024, 4096);
}

// Round 3
// 329.995 us; speedup vs baseline: 1.2301x; 1.1492x over previous
//
#include <hip/hip_runtime.h>
#include <hip/hip_bf16.h>
#include <stdint.h>

#define B_   2
#define S_   2048
#define D_   1024
#define H_   16
#define DH_  64
#define HID_ 4096
#define M_   4096  // B_*S_

typedef __bf16 bf16x8 __attribute__((ext_vector_type(8)));
typedef float  f32x4  __attribute__((ext_vector_type(4)));

typedef const uint32_t __attribute__((address_space(1))) u32g;
typedef uint32_t       __attribute__((address_space(3))) u32l;

__device__ __forceinline__ uint16_t f2bf(float f) {
  uint32_t u = __builtin_bit_cast(uint32_t, f);
  u += 0x7FFFu + ((u >> 16) & 1u);   // RNE
  return (uint16_t)(u >> 16);
}

__device__ __forceinline__ void gload_lds16(const void* g, void* l) {
  __builtin_amdgcn_global_load_lds((u32g*)g, (u32l*)l, 16, 0, 0);
}

// swizzled LDS 16B read: row-major [*][64] bf16 tile, byte ^= (row&7)<<4
__device__ __forceinline__ const bf16x8* lds8p(const uint16_t* base, int row,
                                               int cole) {
  int byt = (cole * 2) ^ ((row & 7) << 4);
  return reinterpret_cast<const bf16x8*>(base + row * 64 + (byt >> 1));
}

// ---------- weight convert + transpose: W (K,N) f32 -> WT (N,K) bf16 ----------
__global__ void wconv_t(const float* __restrict__ W, uint16_t* __restrict__ WT,
                        int K, int N) {
  __shared__ float tile[32][33];
  int n0 = blockIdx.x * 32, k0 = blockIdx.y * 32;
  int tx = threadIdx.x, ty = threadIdx.y;  // (32,8)
#pragma unroll
  for (int i = 0; i < 4; ++i)
    tile[ty + i * 8][tx] = W[(size_t)(k0 + ty + i * 8) * N + n0 + tx];
  __syncthreads();
#pragma unroll
  for (int i = 0; i < 4; ++i)
    WT[(size_t)(n0 + ty + i * 8) * K + k0 + tx] = f2bf(tile[tx][ty + i * 8]);
}

// ---------- layernorm: f32 row (1024) -> bf16 ----------
__global__ __launch_bounds__(256) void ln_k(const float* __restrict__ x,
                                            const float* __restrict__ sc,
                                            const float* __restrict__ sh,
                                            uint16_t* __restrict__ out) {
  int row = blockIdx.x;
  int t = threadIdx.x;
  float4 v = reinterpret_cast<const float4*>(x + (size_t)row * D_)[t];
  float s = v.x + v.y + v.z + v.w;
  float ss = v.x * v.x + v.y * v.y + v.z * v.z + v.w * v.w;
#pragma unroll
  for (int off = 32; off >= 1; off >>= 1) {
    s += __shfl_xor(s, off);
    ss += __shfl_xor(ss, off);
  }
  __shared__ float red[8];
  int wid = t >> 6, lane = t & 63;
  if (lane == 0) { red[wid] = s; red[wid + 4] = ss; }
  __syncthreads();
  s = red[0] + red[1] + red[2] + red[3];
  ss = red[4] + red[5] + red[6] + red[7];
  float mean = s * (1.0f / D_);
  float var = ss * (1.0f / D_) - mean * mean;
  float rstd = rsqrtf(var + 1e-5f);
  float4 g = reinterpret_cast<const float4*>(sc)[t];
  float4 b = reinterpret_cast<const float4*>(sh)[t];
  ushort4 o;
  o.x = f2bf(g.x * (v.x - mean) * rstd + b.x);
  o.y = f2bf(g.y * (v.y - mean) * rstd + b.y);
  o.z = f2bf(g.z * (v.z - mean) * rstd + b.z);
  o.w = f2bf(g.w * (v.w - mean) * rstd + b.w);
  reinterpret_cast<ushort4*>(out + (size_t)row * D_)[t] = o;
}

// ---------- transpose V (bh,s,dh) -> VT (bh,dh,s), bf16 ----------
__global__ void vtrans_k(const uint16_t* __restrict__ V, uint16_t* __restrict__ VT) {
  __shared__ uint16_t tile[32][33];
  int s0 = blockIdx.x * 32, d0 = blockIdx.y * 32, bh = blockIdx.z;
  int tx = threadIdx.x, ty = threadIdx.y;  // (32,8)
  const uint16_t* vb = V + (size_t)bh * S_ * DH_;
  uint16_t* vtb = VT + (size_t)bh * DH_ * S_;
#pragma unroll
  for (int i = 0; i < 4; ++i)
    tile[ty + i * 8][tx] = vb[(size_t)(s0 + ty + i * 8) * DH_ + d0 + tx];
  __syncthreads();
#pragma unroll
  for (int i = 0; i < 4; ++i)
    vtb[(size_t)(d0 + ty + i * 8) * S_ + s0 + tx] = tile[tx][ty + i * 8];
}

// ---------- GEMM: A (M,K) bf16 x BT (N,K) bf16, 128x128 tile, BK=64 ----------
// EPI 0: qkv head-split bf16 store; 1: f32 out = resid + acc + bias; 2: gelu bf16
template <int EPI>
__global__ __launch_bounds__(256) void gemm_bt(
    const uint16_t* __restrict__ A, const uint16_t* __restrict__ BT,
    void* __restrict__ Cout, const float* __restrict__ bias,
    const float* __restrict__ resid, int M, int N, int K) {
  __shared__ uint16_t Asm_[128 * 64];
  __shared__ uint16_t Bsm_[128 * 64];
  int t = threadIdx.x;
  int lane = t & 63, wid = t >> 6;
  int wr = wid >> 1, wc = wid & 1;
  int m0 = blockIdx.y * 128, n0 = blockIdx.x * 128;
  int l15 = lane & 15, lk8 = (lane >> 4) * 8;
  f32x4 acc[4][4] = {};
  for (int k0 = 0; k0 < K; k0 += 64) {
    __syncthreads();
#pragma unroll
    for (int it = 0; it < 4; ++it) {
      int idx = it * 256 + t;
      int r = idx >> 3, c = (idx & 7) * 8;
      gload_lds16(A + (size_t)(m0 + r) * K + k0 + c, &Asm_[idx * 8]);
      gload_lds16(BT + (size_t)(n0 + r) * K + k0 + c, &Bsm_[idx * 8]);
    }
    __syncthreads();
#pragma unroll
    for (int kk = 0; kk < 2; ++kk) {
      bf16x8 a[4], b[4];
#pragma unroll
      for (int mi = 0; mi < 4; ++mi)
        a[mi] = *reinterpret_cast<const bf16x8*>(
            &Asm_[(wr * 64 + mi * 16 + l15) * 64 + kk * 32 + lk8]);
#pragma unroll
      for (int ni = 0; ni < 4; ++ni)
        b[ni] = *reinterpret_cast<const bf16x8*>(
            &Bsm_[(wc * 64 + ni * 16 + l15) * 64 + kk * 32 + lk8]);
#pragma unroll
      for (int mi = 0; mi < 4; ++mi)
#pragma unroll
        for (int ni = 0; ni < 4; ++ni)
          acc[mi][ni] = __builtin_amdgcn_mfma_f32_16x16x32_bf16(
              a[mi], b[ni], acc[mi][ni], 0, 0, 0);
    }
  }
  int lr4 = (lane >> 4) * 4;
#pragma unroll
  for (int mi = 0; mi < 4; ++mi) {
#pragma unroll
    for (int ni = 0; ni < 4; ++ni) {
#pragma unroll
      for (int r = 0; r < 4; ++r) {
        int gm = m0 + wr * 64 + mi * 16 + lr4 + r;
        int gn = n0 + wc * 64 + ni * 16 + l15;
        float v = acc[mi][ni][r];
        if constexpr (EPI == 0) {
          int which = gn >> 10, nc = gn & 1023;
          int h = nc >> 6, dh = nc & 63;
          int b = gm >> 11, s = gm & 2047;
          ((uint16_t*)Cout)[((size_t)which * 32 + b * 16 + h) * (S_ * 64) +
                            (size_t)s * 64 + dh] = f2bf(v);
        } else if constexpr (EPI == 1) {
          ((float*)Cout)[(size_t)gm * N + gn] =
              resid[(size_t)gm * N + gn] + v + bias[gn];
        } else {
          float u = v + bias[gn];
          float y = 0.7978845608028654f * (u + 0.044715f * u * u * u);
          float e = __expf(2.0f * y);
          float th = 1.0f - 2.0f / (e + 1.0f);  // tanh(y), inf-safe
          ((uint16_t*)Cout)[(size_t)gm * N + gn] = f2bf(0.5f * u * (1.0f + th));
        }
      }
    }
  }
}

// ---------- flash causal attention, QBLK=64 (4 waves x 16 rows), KVBLK=64 ----------
// Block processes the q-tile PAIR (qt, 31-qt): (qt+1)+(32-qt)=33 K-tile iters per
// block, constant — removes the causal load imbalance (R2: heaviest CU had 128
// iters vs avg 66 -> kernel was tail-bound at 13.5% occupancy).
// K/V double-buffered + counted-vmcnt prefetch; LDS tiles XOR-swizzled.
__global__ __launch_bounds__(256) void attn_k(const uint16_t* __restrict__ Q,
                                              const uint16_t* __restrict__ Kv,
                                              const uint16_t* __restrict__ VT,
                                              uint16_t* __restrict__ ctx) {
  __shared__ uint16_t Ksm[2][64 * 64];
  __shared__ uint16_t Vsm[2][64 * 64];  // Vt tile: [dh][key]
  __shared__ uint16_t Psm[4][16 * 64];
  int bh = blockIdx.y;
  int t = threadIdx.x, lane = t & 63, wid = t >> 6;
  int l15 = lane & 15, lk8 = (lane >> 4) * 8, lr4 = (lane >> 4) * 4;

  auto STAGE = [&](int kt, int bufi) {
    int k0 = kt * 64;
#pragma unroll
    for (int it = 0; it < 2; ++it) {
      int idx = it * 256 + t;
      int r = idx >> 3, slot = idx & 7;
      int c = (slot ^ (r & 7)) * 8;
      gload_lds16(Kv + ((size_t)bh * S_ + k0 + r) * 64 + c, &Ksm[bufi][idx * 8]);
      gload_lds16(VT + ((size_t)bh * 64 + r) * S_ + k0 + c, &Vsm[bufi][idx * 8]);
    }
  };

  for (int half = 0; half < 2; ++half) {
    int qt = half ? 31 - blockIdx.x : blockIdx.x;
    int q0 = qt * 64;
    bf16x8 qf[2];
#pragma unroll
    for (int kk = 0; kk < 2; ++kk)
      qf[kk] = *reinterpret_cast<const bf16x8*>(
          &Q[((size_t)bh * S_ + q0 + wid * 16 + l15) * 64 + kk * 32 + lk8]);
    f32x4 o[4] = {};
    float mrow[4], lsum[4];
#pragma unroll
    for (int r = 0; r < 4; ++r) { mrow[r] = -3.0e38f; lsum[r] = 0.0f; }

    int nkt = qt + 1;
    STAGE(0, 0);
    for (int kt = 0; kt < nkt; ++kt) {
      int cur = kt & 1;
      if (kt + 1 < nkt) {
        STAGE(kt + 1, cur ^ 1);
        asm volatile("s_waitcnt vmcnt(4)" ::: "memory");  // cur done, next in flight
      } else {
        asm volatile("s_waitcnt vmcnt(0)" ::: "memory");
      }
      __builtin_amdgcn_s_barrier();
      asm volatile("" ::: "memory");
      __builtin_amdgcn_sched_barrier(0);
      const uint16_t* Kb = Ksm[cur];
      const uint16_t* Vb = Vsm[cur];

      f32x4 sf[4] = {};
#pragma unroll
      for (int kk = 0; kk < 2; ++kk)
#pragma unroll
        for (int nt = 0; nt < 4; ++nt) {
          bf16x8 kb = *lds8p(Kb, nt * 16 + l15, kk * 32 + lk8);
          sf[nt] = __builtin_amdgcn_mfma_f32_16x16x32_bf16(qf[kk], kb, sf[nt], 0, 0, 0);
        }
      float sv[4][4];
      if (kt == qt) {  // only the diagonal tile needs masking (wave-uniform)
#pragma unroll
        for (int nt = 0; nt < 4; ++nt)
#pragma unroll
          for (int r = 0; r < 4; ++r) {
            float s = sf[nt][r] * 0.125f;
            int key = nt * 16 + l15;
            int qr = wid * 16 + lr4 + r;
            sv[nt][r] = (key <= qr) ? s : -3.0e38f;
          }
      } else {
#pragma unroll
        for (int nt = 0; nt < 4; ++nt)
#pragma unroll
          for (int r = 0; r < 4; ++r) sv[nt][r] = sf[nt][r] * 0.125f;
      }
      float pmax[4];
#pragma unroll
      for (int r = 0; r < 4; ++r)
        pmax[r] = fmaxf(fmaxf(sv[0][r], sv[1][r]), fmaxf(sv[2][r], sv[3][r]));
#pragma unroll
      for (int off = 8; off >= 1; off >>= 1)
#pragma unroll
        for (int r = 0; r < 4; ++r)
          pmax[r] = fmaxf(pmax[r], __shfl_xor(pmax[r], off));
      float fac[4];
#pragma unroll
      for (int r = 0; r < 4; ++r) {
        float mn = fmaxf(mrow[r], pmax[r]);
        fac[r] = __expf(mrow[r] - mn);
        mrow[r] = mn;
        lsum[r] *= fac[r];
      }
#pragma unroll
      for (int dt = 0; dt < 4; ++dt)
#pragma unroll
        for (int r = 0; r < 4; ++r) o[dt][r] *= fac[r];
      float psum[4] = {0.0f, 0.0f, 0.0f, 0.0f};
#pragma unroll
      for (int nt = 0; nt < 4; ++nt)
#pragma unroll
        for (int r = 0; r < 4; ++r) {
          float p = __expf(sv[nt][r] - mrow[r]);
          psum[r] += p;
          int prow = lr4 + r, pcol = nt * 16 + l15;
          Psm[wid][prow * 64 + ((((pcol * 2) ^ ((prow & 7) << 4))) >> 1)] = f2bf(p);
        }
#pragma unroll
      for (int off = 8; off >= 1; off >>= 1)
#pragma unroll
        for (int r = 0; r < 4; ++r) psum[r] += __shfl_xor(psum[r], off);
#pragma unroll
      for (int r = 0; r < 4; ++r) lsum[r] += psum[r];
      // PV: ctx += P (16q x 64k) @ Vt^T (64k x 64dh)
#pragma unroll
      for (int kk = 0; kk < 2; ++kk) {
        bf16x8 pa = *lds8p(Psm[wid], l15, kk * 32 + lk8);
#pragma unroll
        for (int dt = 0; dt < 4; ++dt) {
          bf16x8 vb = *lds8p(Vb, dt * 16 + l15, kk * 32 + lk8);
          o[dt] = __builtin_amdgcn_mfma_f32_16x16x32_bf16(pa, vb, o[dt], 0, 0, 0);
        }
      }
      asm volatile("s_waitcnt lgkmcnt(0)" ::: "memory");  // reads of cur done
      __builtin_amdgcn_sched_barrier(0);
      __builtin_amdgcn_s_barrier();  // before next iter overwrites buffers
      asm volatile("" ::: "memory");
    }
    int b = bh >> 4, h = bh & 15;
#pragma unroll
    for (int dt = 0; dt < 4; ++dt)
#pragma unroll
      for (int r = 0; r < 4; ++r) {
        int s = q0 + wid * 16 + lr4 + r;
        int dh = dt * 16 + l15;
        ctx[((size_t)(b * S_ + s)) * D_ + h * 64 + dh] = f2bf(o[dt][r] / lsum[r]);
      }
  }
}

extern "C" void kernel_launch(void* const* d_in, const int* in_sizes, int n_in,
                              void* d_out, int out_size, void* d_ws, size_t ws_size,
                              hipStream_t stream) {
  const float* x    = (const float*)d_in[0];
  const float* Wq   = (const float*)d_in[1];
  const float* Wk   = (const float*)d_in[2];
  const float* Wv   = (const float*)d_in[3];
  const float* Wo   = (const float*)d_in[4];
  const float* bo   = (const float*)d_in[5];
  const float* W1   = (const float*)d_in[6];
  const float* b1   = (const float*)d_in[7];
  const float* W2   = (const float*)d_in[8];
  const float* b2   = (const float*)d_in[9];
  const float* ln1s = (const float*)d_in[10];
  const float* ln1b = (const float*)d_in[11];
  const float* ln2s = (const float*)d_in[12];
  const float* ln2b = (const float*)d_in[13];
  float* out = (float*)d_out;
  char* ws = (char*)d_ws;

  const size_t MB = 1024 * 1024;
  uint16_t* WQKVT = (uint16_t*)(ws + 0);        // 6 MB  (3072 x 1024)
  uint16_t* WOT   = (uint16_t*)(ws + 6 * MB);   // 2 MB  (1024 x 1024)
  uint16_t* W1T   = (uint16_t*)(ws + 8 * MB);   // 8 MB  (4096 x 1024)
  uint16_t* W2T   = (uint16_t*)(ws + 16 * MB);  // 8 MB  (1024 x 4096)
  uint16_t* H1    = (uint16_t*)(ws + 24 * MB);  // 8 MB  (LN1 out; reused for LN2 out)
  float*    X1    = (float*)(ws + 32 * MB);     // 16 MB (attn residual, f32)
  uint16_t* QKV   = (uint16_t*)(ws + 48 * MB);  // 24 MB (q,k,v in (bh,s,dh))
  uint16_t* VTb   = (uint16_t*)(ws + 72 * MB);  // 8 MB  (v transposed (bh,dh,s))
  uint16_t* CTX   = (uint16_t*)(ws + 80 * MB);  // 8 MB
  uint16_t* FFH   = (uint16_t*)(ws + 48 * MB);  // 32 MB (reuses dead QKV/VT)

  dim3 b32x8(32, 8);
  // weight convert+transpose (bf16)
  wconv_t<<<dim3(32, 32), b32x8, 0, stream>>>(Wq, WQKVT, 1024, 1024);
  wconv_t<<<dim3(32, 32), b32x8, 0, stream>>>(Wk, WQKVT + 1024 * 1024, 1024, 1024);
  wconv_t<<<dim3(32, 32), b32x8, 0, stream>>>(Wv, WQKVT + 2 * 1024 * 1024, 1024, 1024);
  wconv_t<<<dim3(32, 32), b32x8, 0, stream>>>(Wo, WOT, 1024, 1024);
  wconv_t<<<dim3(128, 32), b32x8, 0, stream>>>(W1, W1T, 1024, 4096);
  wconv_t<<<dim3(32, 128), b32x8, 0, stream>>>(W2, W2T, 4096, 1024);

  // LN1 -> h (bf16)
  ln_k<<<M_, 256, 0, stream>>>(x, ln1s, ln1b, H1);
  // QKV projections (fused N=3072), head-split epilogue
  gemm_bt<0><<<dim3(24, 32), 256, 0, stream>>>(H1, WQKVT, QKV, nullptr, nullptr,
                                               M_, 3072, 1024);
  const uint16_t* Qp = QKV;
  const uint16_t* Kp = QKV + (size_t)32 * S_ * 64;
  const uint16_t* Vp = QKV + (size_t)64 * S_ * 64;
  vtrans_k<<<dim3(64, 2, 32), b32x8, 0, stream>>>(Vp, VTb);
  // flash causal attention (paired q-tiles: grid x = 16 pairs)
  attn_k<<<dim3(16, 32), 256, 0, stream>>>(Qp, Kp, VTb, CTX);
  // Wo projection + bias + residual -> X1 (f32)
  gemm_bt<1><<<dim3(8, 32), 256, 0, stream>>>(CTX, WOT, X1, bo, x, M_, 1024, 1024);
  // LN2 -> h2 (bf16, reuse H1)
  ln_k<<<M_, 256, 0, stream>>>(X1, ln2s, ln2b, H1);
  // FFN1 + GELU -> FFH (bf16)
  gemm_bt<2><<<dim3(32, 32), 256, 0, stream>>>(H1, W1T, FFH, b1, nullptr,
                                               M_, 4096, 1024);
  // FFN2 + bias + residual -> out (f32)
  gemm_bt<1><<<dim3(8, 32), 256, 0, stream>>>(FFH, W2T, out, b2, X1, M_, 1024, 4096);
}